// Round 7
// baseline (231.513 us; speedup 1.0000x reference)
//
#include <hip/hip_runtime.h>
#include <hip/hip_bf16.h>

typedef __bf16 bf16x8 __attribute__((ext_vector_type(8)));
typedef float  f32x4  __attribute__((ext_vector_type(4)));

#define WBT_STRIDE 136   // bf16/row: 80 rows x 128 k; 272B rows (16B-aligned, 2-way banks)
#define H1_STRIDE  104   // bf16/row: 128 rows x 96 k; 208B rows
#define W3T_STRIDE 104   // bf16/row: 48 rows x 96 k

// gathered 8 x dwordx4 facts load: row = compacted local index (register)
#define LOAD_CT(av, rl)                                                         \
    {                                                                           \
        const float* p0 = &fb[(size_t)(wave * 64 + (rl)) * 128 + qd * 8];       \
        _Pragma("unroll")                                                       \
        for (int kc = 0; kc < 4; ++kc) {                                        \
            av[kc][0] = *(const f32x4*)(p0 + kc * 32);                          \
            av[kc][1] = *(const f32x4*)(p0 + kc * 32 + 4);                      \
        }                                                                       \
    }

// f32 -> bf16 MFMA A-fragments (av stays LIVE for the fused output accumulate)
#define CONV_AF(af, av)                                                         \
    _Pragma("unroll")                                                           \
    for (int kc = 0; kc < 4; ++kc)                                              \
        _Pragma("unroll")                                                       \
        for (int i = 0; i < 8; ++i)                                             \
            af[kc][i] = (__bf16)((i < 4) ? av[kc][0][i] : av[kc][1][i - 4]);

// score chain + fused output for one compacted tile:
// GEMM1 -> sigmoid -> LDS -> GEMM2 -> sigmoid -> W4 -> per-row reduce ->
// pm = (slot<cnt) ? exp(score) : 0 -> oacc += pm * av  (exact f32, no pass 2)
#define SCORE_ACC_CT(af, av, tile)                                              \
    {                                                                           \
        /* GEMM1: [16,128]@[128,80] -> sigmoid -> h1 (wave-private LDS slab) */ \
        _Pragma("unroll")                                                       \
        for (int ct = 0; ct < 5; ++ct) {                                        \
            f32x4 acc = {0.f, 0.f, 0.f, 0.f};                                   \
            _Pragma("unroll")                                                   \
            for (int kc = 0; kc < 4; ++kc) {                                    \
                bf16x8 bfr = *(const bf16x8*)&WbT[(ct * 16 + m) * WBT_STRIDE + kc * 32 + qd * 8]; \
                acc = __builtin_amdgcn_mfma_f32_16x16x32_bf16(af[kc], bfr, acc, 0, 0, 0); \
            }                                                                   \
            const int col = ct * 16 + m;  /* C/D: col=lane&15, row=quad*4+r */  \
            const float qc = qcs[col];                                          \
            _Pragma("unroll")                                                   \
            for (int r = 0; r < 4; ++r) {                                       \
                float x = acc[r] + qc;                                          \
                float h = __builtin_amdgcn_rcpf(1.0f + __expf(-x));             \
                h1w[(qd * 4 + r) * H1_STRIDE + col] = (__bf16)h;                \
            }                                                                   \
        }                                                                       \
        asm volatile("s_waitcnt lgkmcnt(0)" ::: "memory"); /* wave-private */   \
        /* GEMM2: [16,96]@[96,48] -> sigmoid -> score = h2 @ W4 */              \
        bf16x8 a2[3];                                                           \
        _Pragma("unroll")                                                       \
        for (int kc = 0; kc < 3; ++kc)                                          \
            a2[kc] = *(const bf16x8*)&h1w[m * H1_STRIDE + kc * 32 + qd * 8];    \
        float sc[4] = {0.f, 0.f, 0.f, 0.f};                                     \
        _Pragma("unroll")                                                       \
        for (int ct = 0; ct < 3; ++ct) {                                        \
            f32x4 acc2 = {0.f, 0.f, 0.f, 0.f};                                  \
            _Pragma("unroll")                                                   \
            for (int kc = 0; kc < 3; ++kc) {                                    \
                bf16x8 bfr = *(const bf16x8*)&W3T[(ct * 16 + m) * W3T_STRIDE + kc * 32 + qd * 8]; \
                acc2 = __builtin_amdgcn_mfma_f32_16x16x32_bf16(a2[kc], bfr, acc2, 0, 0, 0); \
            }                                                                   \
            const int col = ct * 16 + m;                                        \
            const float w4v = w4s[col], b3v = b3s[col];                         \
            _Pragma("unroll")                                                   \
            for (int r = 0; r < 4; ++r) {                                       \
                float h2 = __builtin_amdgcn_rcpf(1.0f + __expf(-(acc2[r] + b3v))); \
                sc[r] = fmaf(h2, w4v, sc[r]);                                   \
            }                                                                   \
        }                                                                       \
        _Pragma("unroll")                                                       \
        for (int d = 1; d < 16; d <<= 1)                                        \
            _Pragma("unroll")                                                   \
            for (int r = 0; r < 4; ++r)                                         \
                sc[r] += __shfl_xor(sc[r], d);                                  \
        /* own-row score via bpermute (row m lives as sc[m&3] in quad m>>2) */  \
        float s0v = __int_as_float(__builtin_amdgcn_ds_bpermute(idx, __float_as_int(sc[0]))); \
        float s1v = __int_as_float(__builtin_amdgcn_ds_bpermute(idx, __float_as_int(sc[1]))); \
        float s2v = __int_as_float(__builtin_amdgcn_ds_bpermute(idx, __float_as_int(sc[2]))); \
        float s3v = __int_as_float(__builtin_amdgcn_ds_bpermute(idx, __float_as_int(sc[3]))); \
        const int rr = m & 3;                                                   \
        float srow = (rr == 0) ? s0v : (rr == 1) ? s1v : (rr == 2) ? s2v : s3v; \
        /* p = (slot<cnt) ? exp(score) : 0  (|score|<=sum|W4|~5; b4 cancels) */ \
        const float pmv = (((tile) * 16 + m) < cnt) ? __expf(srow) : 0.f;       \
        Zl += pmv;                                                              \
        _Pragma("unroll")                                                       \
        for (int kc = 0; kc < 4; ++kc)                                          \
            _Pragma("unroll")                                                   \
            for (int i = 0; i < 4; ++i) {                                       \
                oacc[kc][i]     = fmaf(pmv, av[kc][0][i], oacc[kc][i]);         \
                oacc[kc][i + 4] = fmaf(pmv, av[kc][1][i], oacc[kc][i + 4]);     \
            }                                                                   \
    }

__global__ __launch_bounds__(512, 2)
void attn_fused(const float* __restrict__ query,
                const float* __restrict__ facts,
                const int*   __restrict__ mask,
                const float* __restrict__ W1, const float* __restrict__ b1,
                const float* __restrict__ alpha,
                const float* __restrict__ W2, const float* __restrict__ b2,
                const float* __restrict__ W3, const float* __restrict__ b3,
                const float* __restrict__ W4,
                float* __restrict__ out)
{
    __shared__ __align__(16) __bf16 WbT[80 * WBT_STRIDE];    // folded W2, [n][k]
    __shared__ __align__(16) __bf16 W3T[48 * W3T_STRIDE];    // W3^T zero-padded
    __shared__ __align__(16) __bf16 h1all[128 * H1_STRIDE];  // per-wave 16-row slabs
    __shared__ float qy[128], qs[128], qcs[80];
    __shared__ float qpart[4][128], qcp[4][80];
    __shared__ float w4s[48], b3s[48];
    __shared__ float outw[8 * 128];
    __shared__ unsigned char cidx8[8 * 64];                  // compacted local row idx
    __shared__ float Zw[8];

    const int b = blockIdx.x, t = threadIdx.x;
    const int wave = t >> 6, lane = t & 63, qd = lane >> 4, m = lane & 15;
    const float* fb = facts + (size_t)b * (512 * 128);
    const int*   mb = mask + b * 512;

    // ---- mask compaction: wave ballots its OWN 64 rows; score chain runs on
    // ceil(cnt/16) gathered tiles (~2.5 expected vs 4).  Dead rows (mask=0)
    // contribute nothing to softmax/output, so skipping them is exact.
    const int mvl = mb[wave * 64 + lane];
    const unsigned long long bal = __ballot(mvl == 1);
    const int cnt = __popcll(bal);
    cidx8[wave * 64 + lane] = 0;                             // pad slots -> row 0
    asm volatile("s_waitcnt lgkmcnt(0)" ::: "memory");
    if (mvl == 1) {
        const int rank = __popcll(bal & ((1ull << lane) - 1ull));
        cidx8[wave * 64 + rank] = (unsigned char)lane;
    }
    asm volatile("s_waitcnt lgkmcnt(0)" ::: "memory");
    // hoist this lane's 4 slot->row indices into registers (no LDS on load path)
    const int rl0 = cidx8[wave * 64 +  0 + m];
    const int rl1 = cidx8[wave * 64 + 16 + m];
    const int rl2 = cidx8[wave * 64 + 32 + m];
    const int rl3 = cidx8[wave * 64 + 48 + m];

    // ---- pre-issue ALL compacted facts tiles (up to 128 VGPR of payload).
    // Every load the wave will ever need is in flight before the prologue;
    // their latency hides under weight staging, and pass 1 never stalls on
    // memory.  Buffers stay live so the output accumulate reuses exact f32
    // facts (pass 2 eliminated).  Occupancy drops to 8 waves/CU -- deliberate:
    // deep per-wave pipeline beats shallow-stalling waves for this kernel.
    f32x4 av0[4][2], av1[4][2], av2[4][2], av3[4][2];
    LOAD_CT(av0, rl0)
    if (cnt > 16) LOAD_CT(av1, rl1)
    if (cnt > 32) LOAD_CT(av2, rl2)
    if (cnt > 48) LOAD_CT(av3, rl3)

    // ---- prologue: stage query, build W3^T, zero h1 pad cols, small vecs ----
    if (t < 128) qy[t] = query[b * 128 + t];
    for (int e = t; e < 48 * 96; e += 512) {
        int j = e / 96, k = e % 96;                          // W3 row-major [80][40]
        W3T[j * W3T_STRIDE + k] = (j < 40 && k < 80) ? (__bf16)W3[k * 40 + j]
                                                     : (__bf16)0.0f;
    }
    for (int e = t; e < 128 * 16; e += 512) {                // h1 cols 80..95 := 0
        int r = e >> 4, c = 80 + (e & 15);
        h1all[r * H1_STRIDE + c] = (__bf16)0.0f;
    }
    if (t < 48) { w4s[t] = (t < 40) ? W4[t] : 0.f; b3s[t] = (t < 40) ? b3[t] : 0.f; }
    __syncthreads();

    // q = PReLU(query @ W1 + b1), split-K x4
    {
        int j = t & 127, kh = t >> 7;
        float acc = (kh == 0) ? b1[j] : 0.f;
        const float* w1p = W1 + (kh * 32) * 128 + j;
        #pragma unroll 8
        for (int k = 0; k < 32; ++k) acc = fmaf(qy[kh * 32 + k], w1p[k * 128], acc);
        qpart[kh][j] = acc;
    }
    __syncthreads();
    if (t < 128) {
        float s = (qpart[0][t] + qpart[1][t]) + (qpart[2][t] + qpart[3][t]);
        qs[t] = (s >= 0.f) ? s : alpha[t] * s;
    }
    __syncthreads();

    // qconst = q@(W2a+W2c)+b2 (split-K x4); fold WbT[n][k] = W2b - W2c + q_k*W2d
    if (t < 320) {
        int jj = t % 80, hh = t / 80;
        float acc = (hh == 0) ? b2[jj] : 0.f;
        #pragma unroll 8
        for (int k = hh * 32; k < hh * 32 + 32; ++k)
            acc = fmaf(qs[k], W2[k * 80 + jj] + W2[(256 + k) * 80 + jj], acc);
        qcp[hh][jj] = acc;
    }
    for (int e = t; e < 128 * 80; e += 512) {
        int k = e / 80, n = e - k * 80;
        float w = W2[(128 + k) * 80 + n] - W2[(256 + k) * 80 + n]
                + qs[k] * W2[(384 + k) * 80 + n];
        WbT[n * WBT_STRIDE + k] = (__bf16)w;
    }
    __syncthreads();
    if (t < 80) qcs[t] = (qcp[0][t] + qcp[1][t]) + (qcp[2][t] + qcp[3][t]);
    __syncthreads();

    // ---- pass 1: score+accumulate on compacted tiles (wave-uniform branches)
    __bf16* h1w = &h1all[wave * 16 * H1_STRIDE];
    const int idx = ((((m >> 2) << 4) | m) << 2);            // bpermute selector

    float Zl = 0.f;
    float oacc[4][8];
    #pragma unroll
    for (int kc = 0; kc < 4; ++kc)
        #pragma unroll
        for (int i = 0; i < 8; ++i) oacc[kc][i] = 0.f;
    bf16x8 af[4];

    CONV_AF(af, av0)
    SCORE_ACC_CT(af, av0, 0)
    if (cnt > 16) {
        CONV_AF(af, av1)
        SCORE_ACC_CT(af, av1, 1)
    }
    if (cnt > 32) {
        CONV_AF(af, av2)
        SCORE_ACC_CT(af, av2, 2)
    }
    if (cnt > 48) {
        CONV_AF(af, av3)
        SCORE_ACC_CT(af, av3, 3)
    }

    // ---- epilogue: reduce over m (16-lane butterfly), combine 8 waves ----
    #pragma unroll
    for (int d = 1; d < 16; d <<= 1) {
        #pragma unroll
        for (int kc = 0; kc < 4; ++kc)
            #pragma unroll
            for (int i = 0; i < 8; ++i)
                oacc[kc][i] += __shfl_xor(oacc[kc][i], d);
        Zl += __shfl_xor(Zl, d);
    }
    if (m == 0) {
        #pragma unroll
        for (int kc = 0; kc < 4; ++kc)
            #pragma unroll
            for (int i = 0; i < 8; ++i)
                outw[wave * 128 + kc * 32 + qd * 8 + i] = oacc[kc][i];
        if (lane == 0) Zw[wave] = Zl;
    }
    __syncthreads();

    if (t < 128) {
        float v = 0.f, Z = 0.f;
        #pragma unroll
        for (int w = 0; w < 8; ++w) { v += outw[w * 128 + t]; Z += Zw[w]; }
        out[b * 128 + t] = v / Z;
    }
}

extern "C" void kernel_launch(void* const* d_in, const int* in_sizes, int n_in,
                              void* d_out, int out_size, void* d_ws, size_t ws_size,
                              hipStream_t stream) {
    (void)in_sizes; (void)n_in; (void)d_ws; (void)ws_size; (void)out_size;
    const float* query = (const float*)d_in[0];
    const float* facts = (const float*)d_in[1];
    const int*   mask  = (const int*)d_in[2];
    const float* W1 = (const float*)d_in[3];
    const float* b1 = (const float*)d_in[4];
    const float* al = (const float*)d_in[5];
    const float* W2 = (const float*)d_in[6];
    const float* b2 = (const float*)d_in[7];
    const float* W3 = (const float*)d_in[8];
    const float* b3 = (const float*)d_in[9];
    const float* W4 = (const float*)d_in[10];
    const float* b4 = (const float*)d_in[11];
    (void)b4;  // cancels under softmax
    attn_fused<<<dim3(512), dim3(512), 0, stream>>>(
        query, facts, mask, W1, b1, al, W2, b2, W3, b3, W4, (float*)d_out);
}

// Round 8
// 217.914 us; speedup vs baseline: 1.0624x; 1.0624x over previous
//
#include <hip/hip_runtime.h>
#include <hip/hip_bf16.h>

typedef __bf16 bf16x8 __attribute__((ext_vector_type(8)));
typedef float  f32x4  __attribute__((ext_vector_type(4)));

#define WBT_STRIDE 136   // bf16/row: 80 rows x 128 k; 272B rows (16B-aligned, 2-way banks)
#define H1_STRIDE  104   // bf16/row: 128 rows x 96 k; 208B rows
#define W3T_STRIDE 104   // bf16/row: 48 rows x 96 k

// gathered 8 x dwordx4 facts load: row = compacted local index (register)
#define LOAD_CT(av, rl)                                                         \
    {                                                                           \
        const float* p0 = &fb[(size_t)(wave * 64 + (rl)) * 128 + qd * 8];       \
        _Pragma("unroll")                                                       \
        for (int kc = 0; kc < 4; ++kc) {                                        \
            av[kc][0] = *(const f32x4*)(p0 + kc * 32);                          \
            av[kc][1] = *(const f32x4*)(p0 + kc * 32 + 4);                      \
        }                                                                       \
    }

// f32 -> bf16 MFMA A-fragments; av is DEAD after this (keeps pass-1 pressure low)
#define CONV_AF(af, av)                                                         \
    _Pragma("unroll")                                                           \
    for (int kc = 0; kc < 4; ++kc)                                              \
        _Pragma("unroll")                                                       \
        for (int i = 0; i < 8; ++i)                                             \
            af[kc][i] = (__bf16)((i < 4) ? av[kc][0][i] : av[kc][1][i - 4]);

// score chain for one compacted tile.  GEMM2 uses SWAPPED operands:
// mfma(A=W3T, B=h1) -> D[j-row=ct*16+qd*4+r][s-col=m], so each lane holds the
// h2 pre-activations for ITS OWN facts row m (same LDS reads as unswapped —
// A-row and B-col are both lane&15).  Row-sum over j needs only a 2-stage
// shfl_xor across qd groups; the 4-stage butterfly + 4 bpermutes are gone.
#define SCORE_CT(af, tile)                                                      \
    {                                                                           \
        /* GEMM1: [16,128]@[128,80] -> sigmoid -> h1 (wave-private LDS slab) */ \
        _Pragma("unroll")                                                       \
        for (int ct = 0; ct < 5; ++ct) {                                        \
            f32x4 acc = {0.f, 0.f, 0.f, 0.f};                                   \
            _Pragma("unroll")                                                   \
            for (int kc = 0; kc < 4; ++kc) {                                    \
                bf16x8 bfr = *(const bf16x8*)&WbT[(ct * 16 + m) * WBT_STRIDE + kc * 32 + qd * 8]; \
                acc = __builtin_amdgcn_mfma_f32_16x16x32_bf16(af[kc], bfr, acc, 0, 0, 0); \
            }                                                                   \
            const int col = ct * 16 + m;  /* C/D: col = lane&15, row = quad*4+r */ \
            const float qc = qcs[col];                                          \
            _Pragma("unroll")                                                   \
            for (int r = 0; r < 4; ++r) {                                       \
                float x = acc[r] + qc;                                          \
                float h = __builtin_amdgcn_rcpf(1.0f + __expf(-x));             \
                h1w[(qd * 4 + r) * H1_STRIDE + col] = (__bf16)h;                \
            }                                                                   \
        }                                                                       \
        asm volatile("s_waitcnt lgkmcnt(0)" ::: "memory"); /* wave-private */   \
        /* GEMM2 (swapped): D[j][s=m]; score accumulates on the owner lane */   \
        bf16x8 a2[3];                                                           \
        _Pragma("unroll")                                                       \
        for (int kc = 0; kc < 3; ++kc)                                          \
            a2[kc] = *(const bf16x8*)&h1w[m * H1_STRIDE + kc * 32 + qd * 8];    \
        float sco = 0.f;                                                        \
        _Pragma("unroll")                                                       \
        for (int ct = 0; ct < 3; ++ct) {                                        \
            f32x4 acc2 = {0.f, 0.f, 0.f, 0.f};                                  \
            _Pragma("unroll")                                                   \
            for (int kc = 0; kc < 3; ++kc) {                                    \
                bf16x8 bfr = *(const bf16x8*)&W3T[(ct * 16 + m) * W3T_STRIDE + kc * 32 + qd * 8]; \
                acc2 = __builtin_amdgcn_mfma_f32_16x16x32_bf16(bfr, a2[kc], acc2, 0, 0, 0); \
            }                                                                   \
            _Pragma("unroll")                                                   \
            for (int r = 0; r < 4; ++r) {                                       \
                const int j = ct * 16 + qd * 4 + r;                             \
                float h2 = __builtin_amdgcn_rcpf(1.0f + __expf(-(acc2[r] + b3s[j]))); \
                sco = fmaf(h2, w4s[j], sco);                                    \
            }                                                                   \
        }                                                                       \
        sco += __shfl_xor(sco, 16);                                             \
        sco += __shfl_xor(sco, 32);                                             \
        /* p = (slot<cnt) ? exp(score) : 0  (|score|<=sum|W4|~5; b4 cancels) */ \
        const float pmv = (((tile) * 16 + m) < cnt) ? __expf(sco) : 0.f;        \
        Zl += pmv;                                                              \
        if (qd == 0) pmall[wave * 64 + (tile) * 16 + m] = pmv;                  \
    }

__global__ __launch_bounds__(512, 2)
void attn_fused(const float* __restrict__ query,
                const float* __restrict__ facts,
                const int*   __restrict__ mask,
                const float* __restrict__ W1, const float* __restrict__ b1,
                const float* __restrict__ alpha,
                const float* __restrict__ W2, const float* __restrict__ b2,
                const float* __restrict__ W3, const float* __restrict__ b3,
                const float* __restrict__ W4,
                float* __restrict__ out)
{
    __shared__ __align__(16) __bf16 WbT[80 * WBT_STRIDE];    // folded W2, [n][k]
    __shared__ __align__(16) __bf16 W3T[48 * W3T_STRIDE];    // W3^T zero-padded
    __shared__ __align__(16) __bf16 h1all[128 * H1_STRIDE];  // per-wave 16-row slabs
    __shared__ float qy[128], qs[128], qcs[80];
    __shared__ float qpart[4][128], qcp[4][80];
    __shared__ float w4s[48], b3s[48];
    __shared__ float outw[8 * 128];
    __shared__ float pmall[8 * 64];                          // compacted softmax weights
    __shared__ unsigned char cidx8[8 * 64];                  // compacted local row idx
    __shared__ float Zw[8];

    const int b = blockIdx.x, t = threadIdx.x;
    const int wave = t >> 6, lane = t & 63, qd = lane >> 4, m = lane & 15;
    const float* fb = facts + (size_t)b * (512 * 128);
    const int*   mb = mask + b * 512;

    // ---- mask compaction: wave ballots its OWN 64 rows; score chain runs on
    // ceil(cnt/16) gathered tiles (~2.5 expected vs 4).  Dead rows (mask=0)
    // contribute nothing to softmax/output, so skipping them is exact.
    const int mvl = mb[wave * 64 + lane];
    const unsigned long long bal = __ballot(mvl == 1);
    const int cnt = __popcll(bal);
    cidx8[wave * 64 + lane] = 0;                             // pad slots -> row 0
    asm volatile("s_waitcnt lgkmcnt(0)" ::: "memory");
    if (mvl == 1) {
        const int rank = __popcll(bal & ((1ull << lane) - 1ull));
        cidx8[wave * 64 + rank] = (unsigned char)lane;
    }
    asm volatile("s_waitcnt lgkmcnt(0)" ::: "memory");
    // hoist this lane's 4 slot->row indices into registers (no LDS on load path)
    const int rl0 = cidx8[wave * 64 +  0 + m];
    const int rl1 = cidx8[wave * 64 + 16 + m];
    const int rl2 = cidx8[wave * 64 + 32 + m];
    const int rl3 = cidx8[wave * 64 + 48 + m];

    // ---- pre-issue compacted facts tile 0: HBM latency hides under prologue.
    f32x4 av[4][2];
    LOAD_CT(av, rl0)

    // ---- prologue: stage query, build W3^T, zero h1 pad cols, small vecs ----
    if (t < 128) qy[t] = query[b * 128 + t];
    for (int e = t; e < 48 * 96; e += 512) {
        int j = e / 96, k = e % 96;                          // W3 row-major [80][40]
        W3T[j * W3T_STRIDE + k] = (j < 40 && k < 80) ? (__bf16)W3[k * 40 + j]
                                                     : (__bf16)0.0f;
    }
    for (int e = t; e < 128 * 16; e += 512) {                // h1 cols 80..95 := 0
        int r = e >> 4, c = 80 + (e & 15);
        h1all[r * H1_STRIDE + c] = (__bf16)0.0f;
    }
    if (t < 48) { w4s[t] = (t < 40) ? W4[t] : 0.f; b3s[t] = (t < 40) ? b3[t] : 0.f; }
    __syncthreads();

    // q = PReLU(query @ W1 + b1), split-K x4
    {
        int j = t & 127, kh = t >> 7;
        float acc = (kh == 0) ? b1[j] : 0.f;
        const float* w1p = W1 + (kh * 32) * 128 + j;
        #pragma unroll 8
        for (int k = 0; k < 32; ++k) acc = fmaf(qy[kh * 32 + k], w1p[k * 128], acc);
        qpart[kh][j] = acc;
    }
    __syncthreads();
    if (t < 128) {
        float s = (qpart[0][t] + qpart[1][t]) + (qpart[2][t] + qpart[3][t]);
        qs[t] = (s >= 0.f) ? s : alpha[t] * s;
    }
    __syncthreads();

    // qconst = q@(W2a+W2c)+b2 (split-K x4); fold WbT[n][k] = W2b - W2c + q_k*W2d
    if (t < 320) {
        int jj = t % 80, hh = t / 80;
        float acc = (hh == 0) ? b2[jj] : 0.f;
        #pragma unroll 8
        for (int k = hh * 32; k < hh * 32 + 32; ++k)
            acc = fmaf(qs[k], W2[k * 80 + jj] + W2[(256 + k) * 80 + jj], acc);
        qcp[hh][jj] = acc;
    }
    for (int e = t; e < 128 * 80; e += 512) {
        int k = e / 80, n = e - k * 80;
        float w = W2[(128 + k) * 80 + n] - W2[(256 + k) * 80 + n]
                + qs[k] * W2[(384 + k) * 80 + n];
        WbT[n * WBT_STRIDE + k] = (__bf16)w;
    }
    __syncthreads();
    if (t < 80) qcs[t] = (qcp[0][t] + qcp[1][t]) + (qcp[2][t] + qcp[3][t]);
    __syncthreads();

    // ---- pass 1: scores on compacted tiles (wave-uniform tile-count branches)
    __bf16* h1w = &h1all[wave * 16 * H1_STRIDE];

    float Zl = 0.f;
    bf16x8 af[4];

    CONV_AF(af, av)                  // av(tile0) dead
    if (cnt > 16) LOAD_CT(av, rl1)   // prefetch next tile under this chain
    SCORE_CT(af, 0)
    if (cnt > 16) {
        CONV_AF(af, av)
        if (cnt > 32) LOAD_CT(av, rl2)
        SCORE_CT(af, 1)
    }
    if (cnt > 32) {
        CONV_AF(af, av)
        if (cnt > 48) LOAD_CT(av, rl3)
        SCORE_CT(af, 2)
    }
    if (cnt > 48) {
        CONV_AF(af, av)
        SCORE_CT(af, 3)
    }

    // ---- pass 2: per-lane 2-column stream over exactly cnt compacted rows.
    // oacc = sum_j pm[j]*facts[row_j][col]; rows are L2/L3-warm from pass 1.
    asm volatile("s_waitcnt lgkmcnt(0)" ::: "memory");       // pmall visible in-wave
    float oA = 0.f, oB = 0.f;
    {
        const float* fw = fb + (size_t)(wave * 64) * 128;
        const float* pmw = &pmall[wave * 64];
        const unsigned char* ci = &cidx8[wave * 64];
        #pragma unroll 4
        for (int j = 0; j < cnt; ++j) {
            const float p = pmw[j];
            const int rl = ci[j];
            oA = fmaf(p, fw[rl * 128 + lane], oA);
            oB = fmaf(p, fw[rl * 128 + 64 + lane], oB);
        }
        outw[wave * 128 + lane] = oA;
        outw[wave * 128 + 64 + lane] = oB;
    }

    // Z: lanes m=0..15 of each 16-group hold distinct rows' pm; 16-lane
    // butterfly gives the wave sum (same in every group; lane 0 writes).
    #pragma unroll
    for (int d = 1; d < 16; d <<= 1) Zl += __shfl_xor(Zl, d);
    if (lane == 0) Zw[wave] = Zl;
    __syncthreads();

    if (t < 128) {
        float v = 0.f, Z = 0.f;
        #pragma unroll
        for (int w = 0; w < 8; ++w) { v += outw[w * 128 + t]; Z += Zw[w]; }
        out[b * 128 + t] = v / Z;
    }
}

extern "C" void kernel_launch(void* const* d_in, const int* in_sizes, int n_in,
                              void* d_out, int out_size, void* d_ws, size_t ws_size,
                              hipStream_t stream) {
    (void)in_sizes; (void)n_in; (void)d_ws; (void)ws_size; (void)out_size;
    const float* query = (const float*)d_in[0];
    const float* facts = (const float*)d_in[1];
    const int*   mask  = (const int*)d_in[2];
    const float* W1 = (const float*)d_in[3];
    const float* b1 = (const float*)d_in[4];
    const float* al = (const float*)d_in[5];
    const float* W2 = (const float*)d_in[6];
    const float* b2 = (const float*)d_in[7];
    const float* W3 = (const float*)d_in[8];
    const float* b3 = (const float*)d_in[9];
    const float* W4 = (const float*)d_in[10];
    const float* b4 = (const float*)d_in[11];
    (void)b4;  // cancels under softmax
    attn_fused<<<dim3(512), dim3(512), 0, stream>>>(
        query, facts, mask, W1, b1, al, W2, b2, W3, b3, W4, (float*)d_out);
}